// Round 9
// baseline (311.405 us; speedup 1.0000x reference)
//
#include <hip/hip_runtime.h>
#include <math.h>

#define N_NODES 20000
#define NUM_EDGE 4096
#define DIM 256
#define KF 8
#define EOUT (KF + NUM_EDGE)   /* 4104 */
#define SEL 6001               /* floor(0.3*N)=6000 -> rank<=6000 -> 6001 nodes selected */
#define RPW 5                  /* rows per wave in kAB; 500 blocks x 8 waves x 5 = 20000 */

__device__ __forceinline__ unsigned fkey(float s) {
    unsigned u = __float_as_uint(s);
    return (u & 0x80000000u) ? ~u : (u | 0x80000000u);
}

__device__ __forceinline__ double wred(double v) {
#pragma unroll
    for (int m = 32; m > 0; m >>= 1) v += __shfl_xor(v, m);
    return v;
}

// K0: en[f] = int_emb[f] / max(||int_emb[f]||, 1e-8)
__global__ __launch_bounds__(64) void k0_en(const float* __restrict__ int_emb,
                                            float* __restrict__ en) {
    int f = blockIdx.x, l = threadIdx.x;
    float4 e = ((const float4*)(int_emb + f * DIM))[l];
    double ss = (double)e.x * e.x + (double)e.y * e.y + (double)e.z * e.z + (double)e.w * e.w;
    ss = wred(ss);
    float den = fmaxf((float)sqrt(ss), 1e-8f);
    float4 o;
    o.x = e.x / den; o.y = e.y / den; o.z = e.z / den; o.w = e.w / den;
    ((float4*)(en + f * DIM))[l] = o;
}

// K1: per node (one wave): keys[f][n] = monotone-u32( 10 * <hn, en_f> )
__global__ __launch_bounds__(256) void k1_keys(const float* __restrict__ hidden,
                                               const float* __restrict__ en,
                                               unsigned* __restrict__ keys) {
    int lane = threadIdx.x & 63;
    int n = blockIdx.x * 4 + (threadIdx.x >> 6);
    if (n >= N_NODES) return;
    float4 h = ((const float4*)(hidden + (size_t)n * DIM))[lane];
    double ss = (double)h.x * h.x + (double)h.y * h.y + (double)h.z * h.z + (double)h.w * h.w;
    ss = wred(ss);
    float den = fmaxf((float)sqrt(ss), 1e-8f);
    float hn0 = h.x / den, hn1 = h.y / den, hn2 = h.z / den, hn3 = h.w / den;
    double mydot = 0.0;
#pragma unroll
    for (int f = 0; f < KF; ++f) {
        float4 e = ((const float4*)(en + f * DIM))[lane];
        double d = (double)hn0 * e.x + (double)hn1 * e.y + (double)hn2 * e.z + (double)hn3 * e.w;
        d = wred(d);
        if (lane == f) mydot = d;
    }
    if (lane < KF) {
        float sim = (float)(10.0 * mydot);
        keys[(size_t)lane * N_NODES + n] = fkey(sim);
    }
}

// K2: per factor: radix-select threshold key T, #ties needed, sorted tie list.
__global__ __launch_bounds__(1024) void k2_select(const unsigned* __restrict__ keys,
                                                  unsigned* __restrict__ T, int* __restrict__ need,
                                                  int* __restrict__ eqn, int* __restrict__ eqlist) {
    int f = blockIdx.x, tid = threadIdx.x;
    const unsigned* col = keys + (size_t)f * N_NODES;
    __shared__ unsigned hist[256];
    __shared__ int s_neq;
    unsigned prefix = 0u, pmask = 0u;
    int k = SEL;
    for (int shift = 24; shift >= 0; shift -= 8) {
        if (tid < 256) hist[tid] = 0u;
        __syncthreads();
        for (int i = tid; i < N_NODES; i += 1024) {
            unsigned key = col[i];
            if ((key & pmask) == prefix) atomicAdd(&hist[(key >> shift) & 255u], 1u);
        }
        __syncthreads();
        int acc = 0; unsigned chosen = 0u;   // identical scan in every thread
        for (int b = 255; b >= 0; --b) {
            int c = (int)hist[b];
            if (acc + c >= k) { chosen = (unsigned)b; k -= acc; break; }
            acc += c;
        }
        prefix |= chosen << shift;
        pmask |= 255u << shift;
        __syncthreads();
    }
    if (tid == 0) { T[f] = prefix; need[f] = k; s_neq = 0; }
    __syncthreads();
    for (int i = tid; i < N_NODES; i += 1024) {
        if (col[i] == prefix) {
            int p = atomicAdd(&s_neq, 1);
            if (p < 64) eqlist[f * 64 + p] = i;
        }
    }
    __syncthreads();
    if (tid == 0) {
        int ne = s_neq < 64 ? s_neq : 64;
        for (int a = 1; a < ne; ++a) {
            int v = eqlist[f * 64 + a]; int b = a - 1;
            while (b >= 0 && eqlist[f * 64 + b] > v) { eqlist[f * 64 + b + 1] = eqlist[f * 64 + b]; --b; }
            eqlist[f * 64 + b + 1] = v;
        }
        eqn[f] = ne;
    }
}

// K2.5: per-node selection mask; also zero the u64 degE accumulator (as u32 lanes).
__global__ __launch_bounds__(256) void k25_mask(const unsigned* __restrict__ keys,
                                                const unsigned* __restrict__ T, const int* __restrict__ need,
                                                const int* __restrict__ eqn, const int* __restrict__ eqlist,
                                                unsigned* __restrict__ mask32, unsigned* __restrict__ accum32) {
    int g = blockIdx.x * 256 + threadIdx.x;
    if (g < 2 * EOUT) accum32[g] = 0u;
    if (g >= N_NODES) return;
    unsigned m = 0u;
#pragma unroll
    for (int f = 0; f < KF; ++f) {
        unsigned key = keys[(size_t)f * N_NODES + g];
        unsigned t = T[f];
        bool sel = key > t;
        if (key == t) {
            int ne = eqn[f], nd = need[f], pos = -1;
            for (int i = 0; i < ne; ++i) if (eqlist[f * 64 + i] == g) { pos = i; break; }
            sel = (pos >= 0 && pos < nd);
        }
        m |= (sel ? 1u : 0u) << f;
    }
    mask32[g] = m;
}

// kAB: fused row+column pass, latency-decoupled.
// Phase 1 (per row): 16 loads -> 16 stores + per-lane nonzero BITPACK (2xu32).
//   No wave reduction, no degraw dependency -> next row's loads issue immediately.
// Phase 2 (once per wave): integer wave-reductions of popcounts (5 rows interleaved),
//   degraw/degV/int_H writes, bit-expansion into per-column packed sums, LDS atomics.
// Then one packed u64 global atomic per column per block.
__global__ __launch_bounds__(512, 4) void kAB(const float* __restrict__ H,
                                              const unsigned* __restrict__ mask32,
                                              float* __restrict__ out,
                                              float* __restrict__ degraw_out,
                                              unsigned long long* __restrict__ accum64) {
    __shared__ unsigned lacc[NUM_EDGE];
    int tid = threadIdx.x, lane = tid & 63, w = tid >> 6;
    for (int i = tid; i < NUM_EDGE; i += 512) lacc[i] = 0u;
    __syncthreads();

    int n0 = (blockIdx.x * 8 + w) * RPW;

    // prefetch selection masks for all owned rows
    unsigned m[RPW];
#pragma unroll
    for (int r = 0; r < RPW; ++r) m[r] = mask32[n0 + r];

    unsigned blo[RPW], bhi[RPW];

    // ---- Phase 1: pure streaming ----
#pragma unroll
    for (int r = 0; r < RPW; ++r) {
        int n = n0 + r;
        const float4* hrow = (const float4*)(H + (size_t)n * NUM_EDGE);
        float4* orow = (float4*)(out + (size_t)n * EOUT + KF);
        float4 v[16];
#pragma unroll
        for (int c = 0; c < 16; ++c) v[c] = hrow[c * 64 + lane];
        unsigned lo = 0u, hi = 0u;
#pragma unroll
        for (int c = 0; c < 16; ++c) {
            orow[c * 64 + lane] = v[c];
            unsigned bx = (__float_as_uint(v[c].x) != 0u) ? 1u : 0u;  // H in {0.0f, 1.0f}
            unsigned by = (__float_as_uint(v[c].y) != 0u) ? 1u : 0u;
            unsigned bz = (__float_as_uint(v[c].z) != 0u) ? 1u : 0u;
            unsigned bw = (__float_as_uint(v[c].w) != 0u) ? 1u : 0u;
            int b = (c & 7) * 4;
            unsigned bits = (bx << b) | (by << (b + 1)) | (bz << (b + 2)) | (bw << (b + 3));
            if (c < 8) lo |= bits; else hi |= bits;
        }
        blo[r] = lo; bhi[r] = hi;
    }

    // ---- Phase 2: reductions + stats (off the load critical path) ----
    unsigned rs[RPW];
#pragma unroll
    for (int r = 0; r < RPW; ++r) rs[r] = (unsigned)(__popc(blo[r]) + __popc(bhi[r]));
#pragma unroll
    for (int s = 32; s > 0; s >>= 1) {
#pragma unroll
        for (int r = 0; r < RPW; ++r) rs[r] += __shfl_xor(rs[r], s);
    }

    unsigned packed[RPW];
#pragma unroll
    for (int r = 0; r < RPW; ++r) {
        int n = n0 + r;
        unsigned degraw = rs[r] + 2u * (unsigned)__popc(m[r] & 255u);
        packed[r] = degraw + (1u << 24);
        if (lane < KF)
            out[(size_t)n * EOUT + lane] = ((m[r] >> lane) & 1u) ? 2.0f : 0.0f;
        if (lane == 0) {
            degraw_out[n] = (float)degraw;
            out[(size_t)N_NODES * EOUT + n] =
                (degraw > 0u) ? (float)(1.0 / sqrt((double)degraw)) : 1.0f;
        }
    }

    // expand bits -> per-column packed (sum:24|cnt:8), accumulate into LDS.
    // lacc[cj*64 + lane] holds column (c*64+lane)*4+j (cj=c*4+j):
    // consecutive lanes -> consecutive banks (2 lanes/bank = free).
#pragma unroll
    for (int cj = 0; cj < 64; ++cj) {
        unsigned val = 0u;
#pragma unroll
        for (int r = 0; r < RPW; ++r) {
            unsigned bits = (cj < 32) ? blo[r] : bhi[r];
            if ((bits >> (cj & 31)) & 1u) val += packed[r];
        }
        if (val) atomicAdd(&lacc[cj * 64 + lane], val);
    }
    __syncthreads();

    // LDS -> global packed u64 atomics (one per column per block).
    for (int i = tid; i < NUM_EDGE; i += 512) {
        unsigned p = lacc[i];
        int lane_i = i & 63, cj = i >> 6, c = cj >> 2, j = cj & 3;
        int col = (c * 64 + lane_i) * 4 + j;
        if (p) atomicAdd(&accum64[KF + col],
                         (unsigned long long)(p & 0xFFFFFFu) |
                         ((unsigned long long)(p >> 24) << 32));
    }
}

// kC: degE stats for the KF int_H columns from mask32 + degraw (runs after kAB).
__global__ __launch_bounds__(1024) void kC_int(const unsigned* __restrict__ mask32,
                                               const float* __restrict__ degraw,
                                               unsigned long long* __restrict__ accum64) {
    int f = blockIdx.x, tid = threadIdx.x;
    unsigned su = 0, cn = 0;
    for (int n = tid; n < N_NODES; n += 1024) {
        if ((mask32[n] >> f) & 1u) { su += (unsigned)degraw[n]; cn++; }
    }
    __shared__ unsigned ss[1024], sc[1024];
    ss[tid] = su; sc[tid] = cn;
    __syncthreads();
    for (int s = 512; s > 0; s >>= 1) {
        if (tid < s) { ss[tid] += ss[tid + s]; sc[tid] += sc[tid + s]; }
        __syncthreads();
    }
    if (tid == 0)
        accum64[f] = (unsigned long long)ss[0] | ((unsigned long long)sc[0] << 32);
}

// K4: degE[j] = (sum/max(cnt,1))^-0.5 from packed u64.
__global__ __launch_bounds__(256) void k4_dege(const unsigned long long* __restrict__ accum64,
                                               float* __restrict__ out) {
    int j = blockIdx.x * 256 + threadIdx.x;
    if (j >= EOUT) return;
    unsigned long long a = accum64[j];
    unsigned s = (unsigned)a, c = (unsigned)(a >> 32);
    double mean = (double)s / (double)(c ? c : 1u);
    out[(size_t)N_NODES * EOUT + N_NODES + j] = (float)(1.0 / sqrt(mean));
}

extern "C" void kernel_launch(void* const* d_in, const int* in_sizes, int n_in,
                              void* d_out, int out_size, void* d_ws, size_t ws_size,
                              hipStream_t stream) {
    const float* hidden  = (const float*)d_in[0];
    const float* H       = (const float*)d_in[1];
    const float* int_emb = (const float*)d_in[2];
    float* out = (float*)d_out;
    char* ws = (char*)d_ws;

    // ws layout (bytes): en 8192 | keys 640000 | T 32 | need 32 | eqn 32 | eqlist 2048 |
    //                    mask32 80000 | accum64 32832 (8-aligned: 730368 % 8 == 0)
    // degraw reuses the keys region (keys are dead after k25_mask).
    float*              en      = (float*)ws;
    unsigned*           keys    = (unsigned*)(ws + 8192);
    unsigned*           T       = (unsigned*)(ws + 648192);
    int*                need    = (int*)(ws + 648224);
    int*                eqn     = (int*)(ws + 648256);
    int*                eqlist  = (int*)(ws + 648288);
    unsigned*           mask32  = (unsigned*)(ws + 650336);
    unsigned long long* accum64 = (unsigned long long*)(ws + 730368);
    float*              degraw  = (float*)(ws + 8192);   // aliases keys

    hipLaunchKernelGGL(k0_en,     dim3(8),    dim3(64),   0, stream, int_emb, en);
    hipLaunchKernelGGL(k1_keys,   dim3(5000), dim3(256),  0, stream, hidden, en, keys);
    hipLaunchKernelGGL(k2_select, dim3(8),    dim3(1024), 0, stream, keys, T, need, eqn, eqlist);
    hipLaunchKernelGGL(k25_mask,  dim3(80),   dim3(256),  0, stream, keys, T, need, eqn, eqlist,
                       mask32, (unsigned*)accum64);
    hipLaunchKernelGGL(kAB,       dim3(500),  dim3(512),  0, stream, H, mask32, out, degraw, accum64);
    hipLaunchKernelGGL(kC_int,    dim3(8),    dim3(1024), 0, stream, mask32, degraw, accum64);
    hipLaunchKernelGGL(k4_dege,   dim3(17),   dim3(256),  0, stream, accum64, out);
}

// Round 10
// 299.102 us; speedup vs baseline: 1.0411x; 1.0411x over previous
//
#include <hip/hip_runtime.h>
#include <math.h>

#define N_NODES 20000
#define NUM_EDGE 4096
#define DIM 256
#define KF 8
#define EOUT (KF + NUM_EDGE)   /* 4104 */
#define SEL 6001               /* floor(0.3*N)=6000 -> rank<=6000 -> 6001 nodes selected */
#define RPW 5                  /* rows per wave in kAB */
#define GW  4000               /* total waves in kAB grid: 500 blocks x 8 waves */

__device__ __forceinline__ unsigned fkey(float s) {
    unsigned u = __float_as_uint(s);
    return (u & 0x80000000u) ? ~u : (u | 0x80000000u);
}

__device__ __forceinline__ double wred(double v) {
#pragma unroll
    for (int m = 32; m > 0; m >>= 1) v += __shfl_xor(v, m);
    return v;
}

// K0: en[f] = int_emb[f] / max(||int_emb[f]||, 1e-8)
__global__ __launch_bounds__(64) void k0_en(const float* __restrict__ int_emb,
                                            float* __restrict__ en) {
    int f = blockIdx.x, l = threadIdx.x;
    float4 e = ((const float4*)(int_emb + f * DIM))[l];
    double ss = (double)e.x * e.x + (double)e.y * e.y + (double)e.z * e.z + (double)e.w * e.w;
    ss = wred(ss);
    float den = fmaxf((float)sqrt(ss), 1e-8f);
    float4 o;
    o.x = e.x / den; o.y = e.y / den; o.z = e.z / den; o.w = e.w / den;
    ((float4*)(en + f * DIM))[l] = o;
}

// K1: per node (one wave): keys[f][n] = monotone-u32( 10 * <hn, en_f> )
__global__ __launch_bounds__(256) void k1_keys(const float* __restrict__ hidden,
                                               const float* __restrict__ en,
                                               unsigned* __restrict__ keys) {
    int lane = threadIdx.x & 63;
    int n = blockIdx.x * 4 + (threadIdx.x >> 6);
    if (n >= N_NODES) return;
    float4 h = ((const float4*)(hidden + (size_t)n * DIM))[lane];
    double ss = (double)h.x * h.x + (double)h.y * h.y + (double)h.z * h.z + (double)h.w * h.w;
    ss = wred(ss);
    float den = fmaxf((float)sqrt(ss), 1e-8f);
    float hn0 = h.x / den, hn1 = h.y / den, hn2 = h.z / den, hn3 = h.w / den;
    double mydot = 0.0;
#pragma unroll
    for (int f = 0; f < KF; ++f) {
        float4 e = ((const float4*)(en + f * DIM))[lane];
        double d = (double)hn0 * e.x + (double)hn1 * e.y + (double)hn2 * e.z + (double)hn3 * e.w;
        d = wred(d);
        if (lane == f) mydot = d;
    }
    if (lane < KF) {
        float sim = (float)(10.0 * mydot);
        keys[(size_t)lane * N_NODES + n] = fkey(sim);
    }
}

// K2: per factor: radix-select threshold key T, #ties needed, sorted tie list.
__global__ __launch_bounds__(1024) void k2_select(const unsigned* __restrict__ keys,
                                                  unsigned* __restrict__ T, int* __restrict__ need,
                                                  int* __restrict__ eqn, int* __restrict__ eqlist) {
    int f = blockIdx.x, tid = threadIdx.x;
    const unsigned* col = keys + (size_t)f * N_NODES;
    __shared__ unsigned hist[256];
    __shared__ int s_neq;
    unsigned prefix = 0u, pmask = 0u;
    int k = SEL;
    for (int shift = 24; shift >= 0; shift -= 8) {
        if (tid < 256) hist[tid] = 0u;
        __syncthreads();
        for (int i = tid; i < N_NODES; i += 1024) {
            unsigned key = col[i];
            if ((key & pmask) == prefix) atomicAdd(&hist[(key >> shift) & 255u], 1u);
        }
        __syncthreads();
        int acc = 0; unsigned chosen = 0u;   // identical scan in every thread
        for (int b = 255; b >= 0; --b) {
            int c = (int)hist[b];
            if (acc + c >= k) { chosen = (unsigned)b; k -= acc; break; }
            acc += c;
        }
        prefix |= chosen << shift;
        pmask |= 255u << shift;
        __syncthreads();
    }
    if (tid == 0) { T[f] = prefix; need[f] = k; s_neq = 0; }
    __syncthreads();
    for (int i = tid; i < N_NODES; i += 1024) {
        if (col[i] == prefix) {
            int p = atomicAdd(&s_neq, 1);
            if (p < 64) eqlist[f * 64 + p] = i;
        }
    }
    __syncthreads();
    if (tid == 0) {
        int ne = s_neq < 64 ? s_neq : 64;
        for (int a = 1; a < ne; ++a) {
            int v = eqlist[f * 64 + a]; int b = a - 1;
            while (b >= 0 && eqlist[f * 64 + b] > v) { eqlist[f * 64 + b + 1] = eqlist[f * 64 + b]; --b; }
            eqlist[f * 64 + b + 1] = v;
        }
        eqn[f] = ne;
    }
}

// K2.5: per-node selection mask; also zero the u64 degE accumulator (as u32 lanes).
__global__ __launch_bounds__(256) void k25_mask(const unsigned* __restrict__ keys,
                                                const unsigned* __restrict__ T, const int* __restrict__ need,
                                                const int* __restrict__ eqn, const int* __restrict__ eqlist,
                                                unsigned* __restrict__ mask32, unsigned* __restrict__ accum32) {
    int g = blockIdx.x * 256 + threadIdx.x;
    if (g < 2 * EOUT) accum32[g] = 0u;
    if (g >= N_NODES) return;
    unsigned m = 0u;
#pragma unroll
    for (int f = 0; f < KF; ++f) {
        unsigned key = keys[(size_t)f * N_NODES + g];
        unsigned t = T[f];
        bool sel = key > t;
        if (key == t) {
            int ne = eqn[f], nd = need[f], pos = -1;
            for (int i = 0; i < ne; ++i) if (eqlist[f * 64 + i] == g) { pos = i; break; }
            sel = (pos >= 0 && pos < nd);
        }
        m |= (sel ? 1u : 0u) << f;
    }
    mask32[g] = m;
}

// kAB: fused row+column pass, latency-decoupled, DENSE-WINDOW ordering.
// Wave g owns rows {g, g+GW, g+2GW, ...}: at any instant all ~4000 waves
// read/write inside one dense sliding window (copy-like DRAM locality).
// Phase 1 (per row): 16 loads -> 16 stores + per-lane nonzero bitpack (2xu32).
// Phase 2 (once per wave): popcount wave-reductions, degraw/degV/int_H writes,
// bit-expansion into per-column packed sums (LDS), then one packed u64 global
// atomic per column per block.
__global__ __launch_bounds__(512) void kAB(const float* __restrict__ H,
                                           const unsigned* __restrict__ mask32,
                                           float* __restrict__ out,
                                           float* __restrict__ degraw_out,
                                           unsigned long long* __restrict__ accum64) {
    __shared__ unsigned lacc[NUM_EDGE];
    int tid = threadIdx.x, lane = tid & 63, w = tid >> 6;
    for (int i = tid; i < NUM_EDGE; i += 512) lacc[i] = 0u;
    __syncthreads();

    int gw = blockIdx.x * 8 + w;   // global wave id in [0, GW)

    // prefetch selection masks for all owned rows (wave-uniform scalar loads)
    unsigned m[RPW];
#pragma unroll
    for (int r = 0; r < RPW; ++r) m[r] = mask32[gw + r * GW];

    unsigned blo[RPW], bhi[RPW];

    // ---- Phase 1: pure streaming (dense window) ----
#pragma unroll
    for (int r = 0; r < RPW; ++r) {
        int n = gw + r * GW;
        const float4* hrow = (const float4*)(H + (size_t)n * NUM_EDGE);
        float4* orow = (float4*)(out + (size_t)n * EOUT + KF);
        float4 v[16];
#pragma unroll
        for (int c = 0; c < 16; ++c) v[c] = hrow[c * 64 + lane];
        unsigned lo = 0u, hi = 0u;
#pragma unroll
        for (int c = 0; c < 16; ++c) {
            orow[c * 64 + lane] = v[c];
            unsigned bx = (__float_as_uint(v[c].x) != 0u) ? 1u : 0u;  // H in {0.0f, 1.0f}
            unsigned by = (__float_as_uint(v[c].y) != 0u) ? 1u : 0u;
            unsigned bz = (__float_as_uint(v[c].z) != 0u) ? 1u : 0u;
            unsigned bw = (__float_as_uint(v[c].w) != 0u) ? 1u : 0u;
            int b = (c & 7) * 4;
            unsigned bits = (bx << b) | (by << (b + 1)) | (bz << (b + 2)) | (bw << (b + 3));
            if (c < 8) lo |= bits; else hi |= bits;
        }
        blo[r] = lo; bhi[r] = hi;
    }

    // ---- Phase 2: reductions + stats (off the load critical path) ----
    unsigned rs[RPW];
#pragma unroll
    for (int r = 0; r < RPW; ++r) rs[r] = (unsigned)(__popc(blo[r]) + __popc(bhi[r]));
#pragma unroll
    for (int s = 32; s > 0; s >>= 1) {
#pragma unroll
        for (int r = 0; r < RPW; ++r) rs[r] += __shfl_xor(rs[r], s);
    }

    unsigned packed[RPW];
#pragma unroll
    for (int r = 0; r < RPW; ++r) {
        int n = gw + r * GW;
        unsigned degraw = rs[r] + 2u * (unsigned)__popc(m[r] & 255u);
        packed[r] = degraw + (1u << 24);
        if (lane < KF)
            out[(size_t)n * EOUT + lane] = ((m[r] >> lane) & 1u) ? 2.0f : 0.0f;
        if (lane == 0) {
            degraw_out[n] = (float)degraw;
            out[(size_t)N_NODES * EOUT + n] =
                (degraw > 0u) ? (float)(1.0 / sqrt((double)degraw)) : 1.0f;
        }
    }

    // expand bits -> per-column packed (sum:24|cnt:8), accumulate into LDS.
    // lacc[cj*64 + lane] holds column (c*64+lane)*4+j (cj=c*4+j):
    // consecutive lanes -> consecutive banks (2 lanes/bank = free).
#pragma unroll
    for (int cj = 0; cj < 64; ++cj) {
        unsigned val = 0u;
#pragma unroll
        for (int r = 0; r < RPW; ++r) {
            unsigned bits = (cj < 32) ? blo[r] : bhi[r];
            if ((bits >> (cj & 31)) & 1u) val += packed[r];
        }
        if (val) atomicAdd(&lacc[cj * 64 + lane], val);
    }
    __syncthreads();

    // LDS -> global packed u64 atomics (one per column per block).
    for (int i = tid; i < NUM_EDGE; i += 512) {
        unsigned p = lacc[i];
        int lane_i = i & 63, cj = i >> 6, c = cj >> 2, j = cj & 3;
        int col = (c * 64 + lane_i) * 4 + j;
        if (p) atomicAdd(&accum64[KF + col],
                         (unsigned long long)(p & 0xFFFFFFu) |
                         ((unsigned long long)(p >> 24) << 32));
    }
}

// kC: degE stats for the KF int_H columns from mask32 + degraw (runs after kAB).
__global__ __launch_bounds__(1024) void kC_int(const unsigned* __restrict__ mask32,
                                               const float* __restrict__ degraw,
                                               unsigned long long* __restrict__ accum64) {
    int f = blockIdx.x, tid = threadIdx.x;
    unsigned su = 0, cn = 0;
    for (int n = tid; n < N_NODES; n += 1024) {
        if ((mask32[n] >> f) & 1u) { su += (unsigned)degraw[n]; cn++; }
    }
    __shared__ unsigned ss[1024], sc[1024];
    ss[tid] = su; sc[tid] = cn;
    __syncthreads();
    for (int s = 512; s > 0; s >>= 1) {
        if (tid < s) { ss[tid] += ss[tid + s]; sc[tid] += sc[tid + s]; }
        __syncthreads();
    }
    if (tid == 0)
        accum64[f] = (unsigned long long)ss[0] | ((unsigned long long)sc[0] << 32);
}

// K4: degE[j] = (sum/max(cnt,1))^-0.5 from packed u64.
__global__ __launch_bounds__(256) void k4_dege(const unsigned long long* __restrict__ accum64,
                                               float* __restrict__ out) {
    int j = blockIdx.x * 256 + threadIdx.x;
    if (j >= EOUT) return;
    unsigned long long a = accum64[j];
    unsigned s = (unsigned)a, c = (unsigned)(a >> 32);
    double mean = (double)s / (double)(c ? c : 1u);
    out[(size_t)N_NODES * EOUT + N_NODES + j] = (float)(1.0 / sqrt(mean));
}

extern "C" void kernel_launch(void* const* d_in, const int* in_sizes, int n_in,
                              void* d_out, int out_size, void* d_ws, size_t ws_size,
                              hipStream_t stream) {
    const float* hidden  = (const float*)d_in[0];
    const float* H       = (const float*)d_in[1];
    const float* int_emb = (const float*)d_in[2];
    float* out = (float*)d_out;
    char* ws = (char*)d_ws;

    // ws layout (bytes): en 8192 | keys 640000 | T 32 | need 32 | eqn 32 | eqlist 2048 |
    //                    mask32 80000 | accum64 32832 (8-aligned: 730368 % 8 == 0)
    // degraw reuses the keys region (keys are dead after k25_mask).
    float*              en      = (float*)ws;
    unsigned*           keys    = (unsigned*)(ws + 8192);
    unsigned*           T       = (unsigned*)(ws + 648192);
    int*                need    = (int*)(ws + 648224);
    int*                eqn     = (int*)(ws + 648256);
    int*                eqlist  = (int*)(ws + 648288);
    unsigned*           mask32  = (unsigned*)(ws + 650336);
    unsigned long long* accum64 = (unsigned long long*)(ws + 730368);
    float*              degraw  = (float*)(ws + 8192);   // aliases keys

    hipLaunchKernelGGL(k0_en,     dim3(8),    dim3(64),   0, stream, int_emb, en);
    hipLaunchKernelGGL(k1_keys,   dim3(5000), dim3(256),  0, stream, hidden, en, keys);
    hipLaunchKernelGGL(k2_select, dim3(8),    dim3(1024), 0, stream, keys, T, need, eqn, eqlist);
    hipLaunchKernelGGL(k25_mask,  dim3(80),   dim3(256),  0, stream, keys, T, need, eqn, eqlist,
                       mask32, (unsigned*)accum64);
    hipLaunchKernelGGL(kAB,       dim3(500),  dim3(512),  0, stream, H, mask32, out, degraw, accum64);
    hipLaunchKernelGGL(kC_int,    dim3(8),    dim3(1024), 0, stream, mask32, degraw, accum64);
    hipLaunchKernelGGL(k4_dege,   dim3(17),   dim3(256),  0, stream, accum64, out);
}

// Round 11
// 255.786 us; speedup vs baseline: 1.2174x; 1.1693x over previous
//
#include <hip/hip_runtime.h>
#include <math.h>

#define N_NODES 20000
#define NUM_EDGE 4096
#define DIM 256
#define KF 8
#define EOUT (KF + NUM_EDGE)   /* 4104 */
#define SEL 6001               /* floor(0.3*N)=6000 -> rank<=6000 -> 6001 nodes selected */
#define RPW 10                 /* rows per wave in kAB; 500 blocks x 4 waves x 10 = 20000 */

__device__ __forceinline__ unsigned fkey(float s) {
    unsigned u = __float_as_uint(s);
    return (u & 0x80000000u) ? ~u : (u | 0x80000000u);
}

__device__ __forceinline__ double wred(double v) {
#pragma unroll
    for (int m = 32; m > 0; m >>= 1) v += __shfl_xor(v, m);
    return v;
}
__device__ __forceinline__ float wredf(float v) {
#pragma unroll
    for (int m = 32; m > 0; m >>= 1) v += __shfl_xor(v, m);
    return v;
}

// K0: en[f] = int_emb[f] / max(||int_emb[f]||, 1e-8)
__global__ __launch_bounds__(64) void k0_en(const float* __restrict__ int_emb,
                                            float* __restrict__ en) {
    int f = blockIdx.x, l = threadIdx.x;
    float4 e = ((const float4*)(int_emb + f * DIM))[l];
    double ss = (double)e.x * e.x + (double)e.y * e.y + (double)e.z * e.z + (double)e.w * e.w;
    ss = wred(ss);
    float den = fmaxf((float)sqrt(ss), 1e-8f);
    float4 o;
    o.x = e.x / den; o.y = e.y / den; o.z = e.z / den; o.w = e.w / den;
    ((float4*)(en + f * DIM))[l] = o;
}

// K1: per node (one wave): keys[f][n] = monotone-u32( 10 * <hn, en_f> )
__global__ __launch_bounds__(256) void k1_keys(const float* __restrict__ hidden,
                                               const float* __restrict__ en,
                                               unsigned* __restrict__ keys) {
    int lane = threadIdx.x & 63;
    int n = blockIdx.x * 4 + (threadIdx.x >> 6);
    if (n >= N_NODES) return;
    float4 h = ((const float4*)(hidden + (size_t)n * DIM))[lane];
    double ss = (double)h.x * h.x + (double)h.y * h.y + (double)h.z * h.z + (double)h.w * h.w;
    ss = wred(ss);
    float den = fmaxf((float)sqrt(ss), 1e-8f);
    float hn0 = h.x / den, hn1 = h.y / den, hn2 = h.z / den, hn3 = h.w / den;
    double mydot = 0.0;
#pragma unroll
    for (int f = 0; f < KF; ++f) {
        float4 e = ((const float4*)(en + f * DIM))[lane];
        double d = (double)hn0 * e.x + (double)hn1 * e.y + (double)hn2 * e.z + (double)hn3 * e.w;
        d = wred(d);
        if (lane == f) mydot = d;
    }
    if (lane < KF) {
        float sim = (float)(10.0 * mydot);
        keys[(size_t)lane * N_NODES + n] = fkey(sim);
    }
}

// K2: per factor: radix-select threshold key T, #ties needed, sorted tie list.
__global__ __launch_bounds__(1024) void k2_select(const unsigned* __restrict__ keys,
                                                  unsigned* __restrict__ T, int* __restrict__ need,
                                                  int* __restrict__ eqn, int* __restrict__ eqlist) {
    int f = blockIdx.x, tid = threadIdx.x;
    const unsigned* col = keys + (size_t)f * N_NODES;
    __shared__ unsigned hist[256];
    __shared__ int s_neq;
    unsigned prefix = 0u, pmask = 0u;
    int k = SEL;
    for (int shift = 24; shift >= 0; shift -= 8) {
        if (tid < 256) hist[tid] = 0u;
        __syncthreads();
        for (int i = tid; i < N_NODES; i += 1024) {
            unsigned key = col[i];
            if ((key & pmask) == prefix) atomicAdd(&hist[(key >> shift) & 255u], 1u);
        }
        __syncthreads();
        int acc = 0; unsigned chosen = 0u;   // identical scan in every thread
        for (int b = 255; b >= 0; --b) {
            int c = (int)hist[b];
            if (acc + c >= k) { chosen = (unsigned)b; k -= acc; break; }
            acc += c;
        }
        prefix |= chosen << shift;
        pmask |= 255u << shift;
        __syncthreads();
    }
    if (tid == 0) { T[f] = prefix; need[f] = k; s_neq = 0; }
    __syncthreads();
    for (int i = tid; i < N_NODES; i += 1024) {
        if (col[i] == prefix) {
            int p = atomicAdd(&s_neq, 1);
            if (p < 64) eqlist[f * 64 + p] = i;
        }
    }
    __syncthreads();
    if (tid == 0) {
        int ne = s_neq < 64 ? s_neq : 64;
        for (int a = 1; a < ne; ++a) {
            int v = eqlist[f * 64 + a]; int b = a - 1;
            while (b >= 0 && eqlist[f * 64 + b] > v) { eqlist[f * 64 + b + 1] = eqlist[f * 64 + b]; --b; }
            eqlist[f * 64 + b + 1] = v;
        }
        eqn[f] = ne;
    }
}

// K2.5: per-node selection mask; also zero the u64 degE accumulator (as u32 lanes).
__global__ __launch_bounds__(256) void k25_mask(const unsigned* __restrict__ keys,
                                                const unsigned* __restrict__ T, const int* __restrict__ need,
                                                const int* __restrict__ eqn, const int* __restrict__ eqlist,
                                                unsigned* __restrict__ mask32, unsigned* __restrict__ accum32) {
    int g = blockIdx.x * 256 + threadIdx.x;
    if (g < 2 * EOUT) accum32[g] = 0u;
    if (g >= N_NODES) return;
    unsigned m = 0u;
#pragma unroll
    for (int f = 0; f < KF; ++f) {
        unsigned key = keys[(size_t)f * N_NODES + g];
        unsigned t = T[f];
        bool sel = key > t;
        if (key == t) {
            int ne = eqn[f], nd = need[f], pos = -1;
            for (int i = 0; i < ne; ++i) if (eqlist[f * 64 + i] == g) { pos = i; break; }
            sel = (pos >= 0 && pos < nd);
        }
        m |= (sel ? 1u : 0u) << f;
    }
    mask32[g] = m;
}

// kAB: fused row+column pass (round-4 structure, measured best: 186 us).
// 256 threads (4 waves) x 10 rows/wave, 500 blocks, contiguous rows.
// Per row: stream H row -> row sum (wredf), write H_out row + int_H + degV;
// register-accumulate per-column packed (sum:24|cnt:8); int_H-column stats into
// s_int[8] (kC fused here). Block end: wave->LDS (conflict-free), one packed u64
// global atomic per column per block (sum lo32, cnt hi32 -> exact integers).
__global__ __launch_bounds__(256) void kAB(const float* __restrict__ H,
                                           const unsigned* __restrict__ mask32,
                                           float* __restrict__ out,
                                           unsigned long long* __restrict__ accum64) {
    __shared__ unsigned lacc[NUM_EDGE];
    __shared__ unsigned s_int[KF];
    int tid = threadIdx.x, lane = tid & 63, w = tid >> 6;
    for (int i = tid; i < NUM_EDGE; i += 256) lacc[i] = 0u;
    if (tid < KF) s_int[tid] = 0u;
    __syncthreads();
    unsigned acc[64];
#pragma unroll
    for (int i = 0; i < 64; ++i) acc[i] = 0u;
    int n0 = (blockIdx.x * 4 + w) * RPW;
    for (int r = 0; r < RPW; ++r) {
        int n = n0 + r;
        const float4* hrow = (const float4*)(H + (size_t)n * NUM_EDGE);
        float4* orow = (float4*)(out + (size_t)n * EOUT + KF);
        float4 v[16];
#pragma unroll
        for (int c = 0; c < 16; ++c) v[c] = hrow[c * 64 + lane];
        float rsum = 0.f;
#pragma unroll
        for (int c = 0; c < 16; ++c) {
            orow[c * 64 + lane] = v[c];
            rsum += (v[c].x + v[c].y) + (v[c].z + v[c].w);
        }
        rsum = wredf(rsum);
        unsigned m = mask32[n];
        float degraw = rsum + 2.f * (float)__popc(m & 255u);   // exact small integer
        unsigned packed = (unsigned)degraw + (1u << 24);
        if (lane < KF) {
            unsigned sel = (m >> lane) & 1u;
            out[(size_t)n * EOUT + lane] = sel ? 2.0f : 0.0f;
            if (sel) atomicAdd(&s_int[lane], packed);       // kC fused: int_H col stats
        }
        if (lane == 0)
            out[(size_t)N_NODES * EOUT + n] =
                (degraw > 0.f) ? (float)(1.0 / sqrt((double)degraw)) : 1.0f;
#pragma unroll
        for (int c = 0; c < 16; ++c) {
            if (v[c].x != 0.f) acc[c * 4 + 0] += packed;
            if (v[c].y != 0.f) acc[c * 4 + 1] += packed;
            if (v[c].z != 0.f) acc[c * 4 + 2] += packed;
            if (v[c].w != 0.f) acc[c * 4 + 3] += packed;
        }
    }
    // wave -> LDS. lacc[cj*64 + lane] holds column (c*64+lane)*4+j (cj=c*4+j):
    // consecutive lanes -> consecutive banks (2 lanes/bank = free).
#pragma unroll
    for (int cj = 0; cj < 64; ++cj)
        atomicAdd(&lacc[cj * 64 + lane], acc[cj]);
    __syncthreads();
    // LDS -> global packed u64 atomics (one per column per block).
    for (int i = tid; i < NUM_EDGE; i += 256) {
        unsigned p = lacc[i];
        int lane_i = i & 63, cj = i >> 6, c = cj >> 2, j = cj & 3;
        int col = (c * 64 + lane_i) * 4 + j;
        if (p) atomicAdd(&accum64[KF + col],
                         (unsigned long long)(p & 0xFFFFFFu) |
                         ((unsigned long long)(p >> 24) << 32));
    }
    if (tid < KF) {
        unsigned p = s_int[tid];
        if (p) atomicAdd(&accum64[tid],
                         (unsigned long long)(p & 0xFFFFFFu) |
                         ((unsigned long long)(p >> 24) << 32));
    }
}

// K4: degE[j] = (sum/max(cnt,1))^-0.5 from packed u64.
__global__ __launch_bounds__(256) void k4_dege(const unsigned long long* __restrict__ accum64,
                                               float* __restrict__ out) {
    int j = blockIdx.x * 256 + threadIdx.x;
    if (j >= EOUT) return;
    unsigned long long a = accum64[j];
    unsigned s = (unsigned)a, c = (unsigned)(a >> 32);
    double mean = (double)s / (double)(c ? c : 1u);
    out[(size_t)N_NODES * EOUT + N_NODES + j] = (float)(1.0 / sqrt(mean));
}

extern "C" void kernel_launch(void* const* d_in, const int* in_sizes, int n_in,
                              void* d_out, int out_size, void* d_ws, size_t ws_size,
                              hipStream_t stream) {
    const float* hidden  = (const float*)d_in[0];
    const float* H       = (const float*)d_in[1];
    const float* int_emb = (const float*)d_in[2];
    float* out = (float*)d_out;
    char* ws = (char*)d_ws;

    // ws layout (bytes): en 8192 | keys 640000 | T 32 | need 32 | eqn 32 | eqlist 2048 |
    //                    mask32 80000 | accum64 32832 (8-aligned: 730368 % 8 == 0)
    float*              en      = (float*)ws;
    unsigned*           keys    = (unsigned*)(ws + 8192);
    unsigned*           T       = (unsigned*)(ws + 648192);
    int*                need    = (int*)(ws + 648224);
    int*                eqn     = (int*)(ws + 648256);
    int*                eqlist  = (int*)(ws + 648288);
    unsigned*           mask32  = (unsigned*)(ws + 650336);
    unsigned long long* accum64 = (unsigned long long*)(ws + 730368);

    hipLaunchKernelGGL(k0_en,     dim3(8),    dim3(64),   0, stream, int_emb, en);
    hipLaunchKernelGGL(k1_keys,   dim3(5000), dim3(256),  0, stream, hidden, en, keys);
    hipLaunchKernelGGL(k2_select, dim3(8),    dim3(1024), 0, stream, keys, T, need, eqn, eqlist);
    hipLaunchKernelGGL(k25_mask,  dim3(80),   dim3(256),  0, stream, keys, T, need, eqn, eqlist,
                       mask32, (unsigned*)accum64);
    hipLaunchKernelGGL(kAB,       dim3(500),  dim3(256),  0, stream, H, mask32, out, accum64);
    hipLaunchKernelGGL(k4_dege,   dim3(17),   dim3(256),  0, stream, accum64, out);
}